// Round 7
// baseline (837.895 us; speedup 1.0000x reference)
//
#include <hip/hip_runtime.h>
#include <math.h>

#define N_NODES 50000
#define N_EDGES 800000
#define SCAN_B 512
#define SCAN_NBLK ((N_NODES + SCAN_B - 1) / SCAN_B)   // 98

typedef unsigned int u32;
typedef _Float16 f16;
typedef __fp16 h2 __attribute__((ext_vector_type(2)));   // matches cvt_pkrtz / fdot2

union U32H2 { u32 u; h2 h; };
__device__ __forceinline__ h2 u2h(u32 x) { U32H2 t; t.u = x; return t.h; }
__device__ __forceinline__ u32 h2u(h2 x) { U32H2 t; t.h = x; return t.u; }

// DPP cross-lane move (VALU pipe). 0xB1=xor1(quad), 0x4E=xor2(quad),
// 0x124=row_ror:4, 0x128=row_ror:8; + ds_swizzle xor16 for the cross-row step.
template<int CTRL>
__device__ __forceinline__ h2 dppmov(h2 x) {
    return u2h((u32)__builtin_amdgcn_update_dpp(0, (int)h2u(x), CTRL, 0xF, 0xF, true));
}
__device__ __forceinline__ h2 swz16(h2 x) {
    return u2h((u32)__builtin_amdgcn_ds_swizzle((int)h2u(x), 0x401F));
}

// ---------------- K0: edge MLP (f16 out) + fused degree count ----------------
__global__ void k_edge_mlp(const float* __restrict__ edge_attr,
                           const float* __restrict__ Wm1, const float* __restrict__ bm1,
                           const float* __restrict__ Wm2, const float* __restrict__ bm2,
                           const int* __restrict__ dst, int* __restrict__ deg,
                           f16* __restrict__ e16) {
    int e = blockIdx.x * blockDim.x + threadIdx.x;
    if (e >= N_EDGES) return;
    atomicAdd(&deg[dst[e]], 1);
    const float4* ap = (const float4*)(edge_attr + (size_t)e * 16);
    float a[16];
    #pragma unroll
    for (int i = 0; i < 4; i++) {
        float4 r = ap[i];
        a[4*i] = r.x; a[4*i+1] = r.y; a[4*i+2] = r.z; a[4*i+3] = r.w;
    }
    float g1[16];
    #pragma unroll
    for (int j = 0; j < 16; j++) {
        float v = bm1[j];
        #pragma unroll
        for (int k = 0; k < 16; k++) v = fmaf(a[k], Wm1[k*16 + j], v);
        g1[j] = 0.5f * v * (1.0f + erff(v * 0.70710678118654752f));
    }
    float o[16];
    #pragma unroll
    for (int j = 0; j < 16; j++) {
        float v = bm2[j];
        #pragma unroll
        for (int k = 0; k < 16; k++) v = fmaf(g1[k], Wm2[k*16 + j], v);
        o[j] = v;
    }
    u32 w[8];
    #pragma unroll
    for (int k2 = 0; k2 < 8; k2++) w[k2] = h2u(__builtin_amdgcn_cvt_pkrtz(o[2*k2], o[2*k2+1]));
    uint4* op = (uint4*)(e16 + (size_t)e * 16);
    op[0] = make_uint4(w[0], w[1], w[2], w[3]);
    op[1] = make_uint4(w[4], w[5], w[6], w[7]);
}

// ---------------- K1: node features -> XLt/XRt [n][c][8 inst] f16 ------------
template<int K>
__global__ void __launch_bounds__(512)
k_node_feats(const float* __restrict__ in,
             const float* __restrict__ Wl, const float* __restrict__ bl,
             const float* __restrict__ Wr, const float* __restrict__ br,
             f16* __restrict__ XLt, f16* __restrict__ XRt, int inst_base) {
    int w = threadIdx.x >> 6;
    int c = threadIdx.x & 63;
    int g = w & 3;
    bool isR = w >= 4;
    const float* W = isR ? Wr : Wl;
    const float* bias = isR ? br : bl;
    f16* out = isR ? XRt : XLt;
    int inst = inst_base + g;
    float wcol[K];
    #pragma unroll
    for (int k = 0; k < K; k++) wcol[k] = W[(g*K + k)*64 + c];
    float b = bias[g*64 + c];
    for (int n = blockIdx.x; n < N_NODES; n += gridDim.x) {
        const float* row = in + (size_t)n * K;   // wave-uniform -> scalar loads
        float acc = b;
        #pragma unroll
        for (int k = 0; k < K; k++) acc = fmaf(row[k], wcol[k], acc);
        out[((size_t)n*64 + c)*8 + inst] = (f16)acc;
    }
}

// ---------------- K2: CSR build (scan + fill) ----------------
__global__ void __launch_bounds__(SCAN_B)
k_scan1(const int* __restrict__ deg, int* __restrict__ tmp, int* __restrict__ partials) {
    __shared__ int s[SCAN_B];
    int t = threadIdx.x;
    int i = blockIdx.x * SCAN_B + t;
    int v = (i < N_NODES) ? deg[i] : 0;
    s[t] = v;
    __syncthreads();
    #pragma unroll
    for (int off = 1; off < SCAN_B; off <<= 1) {
        int add = (t >= off) ? s[t - off] : 0;
        __syncthreads();
        s[t] += add;
        __syncthreads();
    }
    if (i < N_NODES) tmp[i] = s[t];
    if (t == SCAN_B - 1) partials[blockIdx.x] = s[SCAN_B - 1];
}

__global__ void __launch_bounds__(64)
k_scan2(int* __restrict__ partials) {
    int lane = threadIdx.x;
    int carry = 0;
    for (int base = 0; base < SCAN_NBLK; base += 64) {
        int i = base + lane;
        int v = (i < SCAN_NBLK) ? partials[i] : 0;
        #pragma unroll
        for (int off = 1; off < 64; off <<= 1) {
            int u = __shfl_up(v, off);
            if (lane >= off) v += u;
        }
        if (i < SCAN_NBLK) partials[i] = v + carry;
        carry += __shfl(v, 63);
    }
}

__global__ void __launch_bounds__(SCAN_B)
k_scan3(const int* __restrict__ tmp, const int* __restrict__ partials,
        int* __restrict__ row_ptr, int* __restrict__ cursor) {
    int i = blockIdx.x * SCAN_B + threadIdx.x;
    if (i < N_NODES) {
        int b = blockIdx.x;
        int off = (b > 0) ? partials[b - 1] : 0;
        row_ptr[i + 1] = off + tmp[i];
        cursor[i] = 0;
        if (i == 0) row_ptr[0] = 0;
    }
}

__global__ void k_fill(const int* __restrict__ dst, const int* __restrict__ row_ptr,
                       int* __restrict__ cursor, int* __restrict__ sorted_eid) {
    int e = blockIdx.x * blockDim.x + threadIdx.x;
    if (e < N_EDGES) {
        int d = dst[e];
        int pos = atomicAdd(&cursor[d], 1);
        sorted_eid[row_ptr[d] + pos] = e;
    }
}

// ---------------- K3: edge-parallel score+exp ----------------
// 4 waves/block, each wave handles 8 consecutive edges (2 groups of 4).
// All loads coalesced or wave-uniform; no readlane; no serial dependence.
// Writes p16[e][head][8 inst] f16.
__global__ void __launch_bounds__(256)
k_edge_score(const int* __restrict__ srcp, const int* __restrict__ dstp,
             const f16* __restrict__ e16,
             const f16* __restrict__ XLt, const f16* __restrict__ XRt,
             const float* __restrict__ Wex, const float* __restrict__ Weh,
             const float* __restrict__ attx, const float* __restrict__ atth,
             f16* __restrict__ p16) {
    int wv = threadIdx.x >> 6;
    int lane = threadIdx.x & 63;
    int c = lane;
    int hh = c >> 5;
    int ch = c & 31;
    int e0 = (blockIdx.x * 4 + wv) * 8;   // 25000 blocks * 4 waves * 8 edges = 800000

    h2 attp[4];
    #pragma unroll
    for (int pr = 0; pr < 4; pr++) {
        int i0 = 2*pr, i1 = 2*pr + 1;
        float a0 = (i0 < 4) ? attx[(i0*2 + hh)*32 + ch] : atth[((i0-4)*2 + hh)*32 + ch];
        float a1 = (i1 < 4) ? attx[(i1*2 + hh)*32 + ch] : atth[((i1-4)*2 + hh)*32 + ch];
        attp[pr] = __builtin_amdgcn_cvt_pkrtz(a0, a1);
    }
    h2 wef[8][8];
    #pragma unroll
    for (int g = 0; g < 4; g++) {
        #pragma unroll
        for (int k2 = 0; k2 < 8; k2++) {
            wef[g][k2]     = __builtin_amdgcn_cvt_pkrtz(Wex[(g*16 + 2*k2)*64 + c],
                                                        Wex[(g*16 + 2*k2 + 1)*64 + c]);
            wef[4 + g][k2] = __builtin_amdgcn_cvt_pkrtz(Weh[(g*16 + 2*k2)*64 + c],
                                                        Weh[(g*16 + 2*k2 + 1)*64 + c]);
        }
    }
    // 8 edges' src/dst (wave-uniform scalar loads)
    int4 sa = *(const int4*)(srcp + e0);
    int4 sb = *(const int4*)(srcp + e0 + 4);
    int4 da = *(const int4*)(dstp + e0);
    int4 db = *(const int4*)(dstp + e0 + 4);
    int ss[8] = {sa.x, sa.y, sa.z, sa.w, sb.x, sb.y, sb.z, sb.w};
    int dd[8] = {da.x, da.y, da.z, da.w, db.x, db.y, db.z, db.w};

    #pragma unroll
    for (int g4 = 0; g4 < 2; g4++) {
        uint4 xl4[4], xr4[4], q0[4], q1[4];
        #pragma unroll
        for (int u = 0; u < 4; u++) {
            int t = g4*4 + u;
            xl4[u] = *(const uint4*)(XLt + ((size_t)ss[t]*64 + c)*8);
            xr4[u] = *(const uint4*)(XRt + ((size_t)dd[t]*64 + c)*8);
            const uint4* ep = (const uint4*)(e16 + (size_t)(e0 + t)*16);
            q0[u] = ep[0]; q1[u] = ep[1];
        }
        #pragma unroll
        for (int u = 0; u < 4; u++) {
            h2 es[8] = {u2h(q0[u].x), u2h(q0[u].y), u2h(q0[u].z), u2h(q0[u].w),
                        u2h(q1[u].x), u2h(q1[u].y), u2h(q1[u].z), u2h(q1[u].w)};
            h2 xlp[4] = {u2h(xl4[u].x), u2h(xl4[u].y), u2h(xl4[u].z), u2h(xl4[u].w)};
            h2 xrp[4] = {u2h(xr4[u].x), u2h(xr4[u].y), u2h(xr4[u].z), u2h(xr4[u].w)};
            float m[8];
            #pragma unroll
            for (int pr = 0; pr < 4; pr++) {
                h2 s = xlp[pr] + xrp[pr];          // v_pk_add_f16
                m[2*pr]   = (float)s[0];
                m[2*pr+1] = (float)s[1];
            }
            #pragma unroll
            for (int inst = 0; inst < 8; inst++) {
                #pragma unroll
                for (int k2 = 0; k2 < 8; k2++)
                    m[inst] = __builtin_amdgcn_fdot2(es[k2], wef[inst][k2], m[inst], false);
            }
            h2 tp[4];
            #pragma unroll
            for (int pr = 0; pr < 4; pr++) {
                h2 mm = __builtin_amdgcn_cvt_pkrtz(m[2*pr], m[2*pr+1]);
                h2 mx = __builtin_elementwise_max(mm, (h2)0);
                h2 mn = __builtin_elementwise_min(mm, (h2)0);
                h2 mr = mn * (h2)0.2f16 + mx;      // leaky_relu, packed
                tp[pr] = mr * attp[pr];
            }
            // rotation-reduce within 16-row (DPP, VALU pipe), then xor16 (1 DS op)
            #pragma unroll
            for (int pr = 0; pr < 4; pr++) tp[pr] = tp[pr] + dppmov<0xB1>(tp[pr]);
            #pragma unroll
            for (int pr = 0; pr < 4; pr++) tp[pr] = tp[pr] + dppmov<0x4E>(tp[pr]);
            #pragma unroll
            for (int pr = 0; pr < 4; pr++) tp[pr] = tp[pr] + dppmov<0x124>(tp[pr]);
            #pragma unroll
            for (int pr = 0; pr < 4; pr++) tp[pr] = tp[pr] + dppmov<0x128>(tp[pr]);
            #pragma unroll
            for (int pr = 0; pr < 4; pr++) tp[pr] = tp[pr] + swz16(tp[pr]);
            // scores tiny (|s| << 1): exp without max-subtraction is equivalent
            u32 pw[4];
            #pragma unroll
            for (int pr = 0; pr < 4; pr++) {
                float p0 = __expf((float)tp[pr][0]);
                float p1 = __expf((float)tp[pr][1]);
                pw[pr] = h2u(__builtin_amdgcn_cvt_pkrtz(p0, p1));
            }
            if ((lane & 31) == 0) {
                uint4 o = make_uint4(pw[0], pw[1], pw[2], pw[3]);
                *(uint4*)(p16 + ((size_t)(e0 + g4*4 + u)*2 + hh)*8) = o;
            }
        }
    }
}

// ---------------- K4: node-parallel aggregate + LSTM + LayerNorm -------------
// 4 waves/block, wave per node. Per edge: 2 broadcast loads + 8 pk ops.
__global__ void __launch_bounds__(256)
k_aggregate(const f16* __restrict__ p16, const f16* __restrict__ XLt,
            const int* __restrict__ row_ptr, const int* __restrict__ sorted_eid,
            const int* __restrict__ src_idx,
            const float* __restrict__ biasx, const float* __restrict__ biash,
            const float* __restrict__ c_prev,
            const float* __restrict__ ln_g, const float* __restrict__ ln_b,
            float* __restrict__ out) {
    int wv = threadIdx.x >> 6;
    int lane = threadIdx.x & 63;
    int n = blockIdx.x * 4 + wv;          // 50000 = 12500*4
    int c = lane;
    int hh = c >> 5;

    h2 accp[4], denp[4];
    #pragma unroll
    for (int pr = 0; pr < 4; pr++) { accp[pr] = (h2)0; denp[pr] = (h2)0; }

    int start = row_ptr[n];
    int end = row_ptr[n + 1];
    for (int base = start; base < end; base += 64) {
        int rem = end - base;
        int cnt = rem < 64 ? rem : 64;
        int eidl = 0, srcl = 0;
        if (base + lane < end) {
            eidl = sorted_eid[base + lane];
            srcl = src_idx[eidl];
        }
        for (int j = 0; j < cnt; j += 4) {
            int m4 = cnt - j; if (m4 > 4) m4 = 4;
            uint4 pl[4], xll[4];
            #pragma unroll
            for (int u = 0; u < 4; u++) {
                if (u < m4) {
                    int eid = __builtin_amdgcn_readlane(eidl, j + u);
                    int sn  = __builtin_amdgcn_readlane(srcl, j + u);
                    pl[u]  = *(const uint4*)(p16 + ((size_t)eid*2 + hh)*8);
                    xll[u] = *(const uint4*)(XLt + ((size_t)sn*64 + c)*8);
                }
            }
            #pragma unroll
            for (int u = 0; u < 4; u++) {
                if (u < m4) {
                    h2 pp[4]  = {u2h(pl[u].x),  u2h(pl[u].y),  u2h(pl[u].z),  u2h(pl[u].w)};
                    h2 xlp[4] = {u2h(xll[u].x), u2h(xll[u].y), u2h(xll[u].z), u2h(xll[u].w)};
                    #pragma unroll
                    for (int pr = 0; pr < 4; pr++) {
                        denp[pr] = denp[pr] + pp[pr];
                        accp[pr] = __builtin_elementwise_fma(pp[pr], xlp[pr], accp[pr]);
                    }
                }
            }
        }
    }
    float gates[4];
    #pragma unroll
    for (int g = 0; g < 4; g++) {
        float ax = (float)accp[g >> 1][g & 1] / ((float)denp[g >> 1][g & 1] + 1e-16f)
                   + biasx[g*64 + c];
        int i = 4 + g;
        float ah = (float)accp[i >> 1][i & 1] / ((float)denp[i >> 1][i & 1] + 1e-16f)
                   + biash[g*64 + c];
        gates[g] = ax + ah;
    }
    float it = 1.f / (1.f + __expf(-gates[0]));
    float ft = 1.f / (1.f + __expf(-gates[1]));
    float ot = 1.f / (1.f + __expf(-gates[2]));
    float gt = tanhf(gates[3]);
    float cp = c_prev[(size_t)n*64 + c];
    float ct = ft * cp + it * gt;
    float ht = ot * tanhf(ct);
    float s1 = ht;
    #pragma unroll
    for (int off = 32; off >= 1; off >>= 1) s1 += __shfl_xor(s1, off);
    float mu = s1 * (1.f / 64.f);
    float d = ht - mu;
    float s2 = d * d;
    #pragma unroll
    for (int off = 32; off >= 1; off >>= 1) s2 += __shfl_xor(s2, off);
    float var = s2 * (1.f / 64.f);
    float y = d * rsqrtf(var + 1e-5f) * ln_g[c] + ln_b[c];
    out[(size_t)n*64 + c] = y;
    out[(size_t)(N_NODES + n)*64 + c] = ct;
}

extern "C" void kernel_launch(void* const* d_in, const int* in_sizes, int n_in,
                              void* d_out, int out_size, void* d_ws, size_t ws_size,
                              hipStream_t stream) {
    const float* x_t    = (const float*)d_in[0];
    const float* h_prev = (const float*)d_in[1];
    const float* c_prev = (const float*)d_in[2];
    const int*   ei     = (const int*)d_in[3];
    const float* eattr  = (const float*)d_in[4];
    const float* Wm1    = (const float*)d_in[5];
    const float* bm1    = (const float*)d_in[6];
    const float* Wm2    = (const float*)d_in[7];
    const float* bm2    = (const float*)d_in[8];
    const float* Wlx    = (const float*)d_in[9];
    const float* blx    = (const float*)d_in[10];
    const float* Wrx    = (const float*)d_in[11];
    const float* brx    = (const float*)d_in[12];
    const float* Wex    = (const float*)d_in[13];
    const float* attx   = (const float*)d_in[14];
    const float* biasx  = (const float*)d_in[15];
    const float* Wlh    = (const float*)d_in[16];
    const float* blh    = (const float*)d_in[17];
    const float* Wrh    = (const float*)d_in[18];
    const float* brh    = (const float*)d_in[19];
    const float* Weh    = (const float*)d_in[20];
    const float* atth   = (const float*)d_in[21];
    const float* biash  = (const float*)d_in[22];
    const float* ln_g   = (const float*)d_in[23];
    const float* ln_b   = (const float*)d_in[24];

    char* ws = (char*)d_ws;
    f16*   e16     = (f16*)(ws + 0);              // 25,600,000 B
    f16*   XLt     = (f16*)(ws + 25600000);       // 51,200,000 B  [n][64][8]
    f16*   XRt     = (f16*)(ws + 76800000);       // 51,200,000 B  [n][64][8]
    f16*   p16     = (f16*)(ws + 128000000);      // 25,600,000 B  [e][2][8]
    int*   row_ptr = (int*)(ws + 153600000);      //    200,016 B
    int*   degcur  = (int*)(ws + 153800016);      //    200,000 B
    int*   sorted  = (int*)(ws + 154000016);      //  3,200,000 B (total 157,200,016)
    int*   scan_tmp = (int*)(ws + 154000016);     // overlaps sorted (dead before k_fill)
    int*   partials = (int*)(ws + 154000016 + 204800);

    const int* srcp = ei;
    const int* dstp = ei + N_EDGES;

    (void)hipMemsetAsync(degcur, 0, N_NODES * sizeof(int), stream);

    k_edge_mlp<<<(N_EDGES + 255) / 256, 256, 0, stream>>>(eattr, Wm1, bm1, Wm2, bm2,
                                                          dstp, degcur, e16);
    k_node_feats<32><<<6250, 512, 0, stream>>>(x_t, Wlx, blx, Wrx, brx, XLt, XRt, 0);
    k_node_feats<64><<<6250, 512, 0, stream>>>(h_prev, Wlh, blh, Wrh, brh, XLt, XRt, 4);
    k_scan1<<<SCAN_NBLK, SCAN_B, 0, stream>>>(degcur, scan_tmp, partials);
    k_scan2<<<1, 64, 0, stream>>>(partials);
    k_scan3<<<SCAN_NBLK, SCAN_B, 0, stream>>>(scan_tmp, partials, row_ptr, degcur);
    k_fill<<<(N_EDGES + 255) / 256, 256, 0, stream>>>(dstp, row_ptr, degcur, sorted);
    k_edge_score<<<25000, 256, 0, stream>>>(srcp, dstp, e16, XLt, XRt,
                                            Wex, Weh, attx, atth, p16);
    k_aggregate<<<12500, 256, 0, stream>>>(p16, XLt, row_ptr, sorted, srcp,
                                           biasx, biash, c_prev, ln_g, ln_b,
                                           (float*)d_out);
}